// Round 17
// baseline (153.119 us; speedup 1.0000x reference)
//
#include <hip/hip_runtime.h>
#include <hip/hip_bf16.h>
#include <math.h>

#define BATCH 4096
#define CTX 20
#define DIM 128
#define NSAMP 8192
#define NCHUNK 64   // 8192 / 128 column-chunks in the GEMM kernel
#define NGROUP (BATCH / 256)   // 16 row-groups

typedef __attribute__((ext_vector_type(8))) short short8;
typedef __attribute__((ext_vector_type(4))) float f32x4;

__device__ __forceinline__ unsigned short f2bf(float x) {
    union { float f; unsigned u; } v; v.f = x;
    unsigned r = v.u + 0x7FFFu + ((v.u >> 16) & 1u);   // round-to-nearest-even
    return (unsigned short)(r >> 16);
}

// ---- Eigen plog<float>, EXACT op schedule — VERIFIED BIT-MATCH vs the
// harness np reference (R13 pass). DO NOT TOUCH.
__device__ __forceinline__ float eigen_plogf(float xf) {
    union { float f; unsigned u; } v; v.f = xf;    // x >= 1, normal, finite
    int ei = (int)((v.u >> 23) & 0xFFu) - 126;     // pfrexp: x = m*2^e, m in [0.5,1)
    v.u = (v.u & 0x007FFFFFu) | 0x3F000000u;
    float x = v.f;
    float e = (float)ei;
    bool msk = x < 0.707106781186547524f;          // x < SQRTHF
    float tmp = msk ? x : 0.0f;                    // pand(x, mask)
    x = __fsub_rn(x, 1.0f);
    e = __fsub_rn(e, msk ? 1.0f : 0.0f);
    x = __fadd_rn(x, tmp);

    float x2 = __fmul_rn(x, x);
    float x3 = __fmul_rn(x2, x);

    float y, y1, y2;
    y  = __builtin_fmaf( 7.0376836292E-2f, x, -1.1514610310E-1f);  // p0,p1
    y1 = __builtin_fmaf(-1.2420140846E-1f, x,  1.4249322787E-1f);  // p3,p4
    y2 = __builtin_fmaf( 2.0000714765E-1f, x, -2.4999993993E-1f);  // p6,p7
    y  = __builtin_fmaf(y,  x,  1.1676998740E-1f);                 // +p2
    y1 = __builtin_fmaf(y1, x, -1.6668057665E-1f);                 // +p5
    y2 = __builtin_fmaf(y2, x,  3.3333331174E-1f);                 // +p8
    y  = __builtin_fmaf(y,  x3, y1);
    y  = __builtin_fmaf(y,  x3, y2);
    y  = __fmul_rn(y, x3);                         // pmul

    y1  = __fmul_rn(e, -2.12194440e-4f);           // pmul (q1) — NOT fused
    tmp = __fmul_rn(x2, 0.5f);                     // pmul — NOT fused
    y   = __fadd_rn(y, y1);                        // padd
    x   = __fsub_rn(x, tmp);                       // psub (x first!)
    y2  = __fmul_rn(e, 0.693359375f);              // pmul (q2) — NOT fused
    x   = __fadd_rn(x, y);                         // padd
    x   = __fadd_rn(x, y2);                        // padd
    return x;
}

__device__ __forceinline__ float log_expected_count(int id) {
    float idf = (float)id;                           // exact (id < 2^24)
    float l2 = eigen_plogf(__fadd_rn(idf, 2.0f));
    float l1 = eigen_plogf(__fadd_rn(idf, 1.0f));
    float num = __fsub_rn(l2, l1);                   // the f32 cancellation
    float logH = eigen_plogf(1000001.0f);
    float p = num / logH;
    float t = __fmul_rn(8192.0f, log1pf(-p));        // *2^13 exact
    float e = -expm1f(t);
    e = fmaxf(e, 1e-38f);
    return logf(e);
}

// Fragment layout: element (row, k) of a [N x 128] bf16 matrix lives at
// ushort offset ((row>>4)*4 + (k>>5))*512 + (((k>>3)&3)*16 + (row&15))*8 + (k&7).
__device__ __forceinline__ size_t frag_off(int row, int k0) {
    return (size_t)(((row >> 4) * 4 + (k0 >> 5)) * 512) +
           ((((k0 >> 3) & 3) * 16 + (row & 15)) * 8) + (k0 & 7);
}

// ---- kernel 1: 256-thread blocks, 1 wave = 1 task. Also zeroes gemm counters.
__global__ __launch_bounds__(256) void k_prep(
        const int* __restrict__ ids, const int* __restrict__ labels,
        const int* __restrict__ sampled,
        const float* __restrict__ in_emb, const float* __restrict__ out_emb,
        const float* __restrict__ bias,
        unsigned short* __restrict__ h_frag, unsigned short* __restrict__ w_frag,
        float* __restrict__ tl, float* __restrict__ sb,
        unsigned int* __restrict__ counters) {
    int tid  = threadIdx.x;
    if (blockIdx.x == 0 && tid < NGROUP) counters[tid] = 0;
    int lane = tid & 63;
    int wv   = tid >> 6;
    int task = blockIdx.x * 4 + wv;
    int half = lane >> 5;             // 0: lanes 0-31, 1: lanes 32-63
    int m    = lane & 31;             // dim group: dims 4m..4m+3
    int k0   = 4 * m;

    if (task < BATCH) {
        int b = task;
        float4 s4 = make_float4(0.f, 0.f, 0.f, 0.f);
#pragma unroll
        for (int c = 0; c < CTX; c += 2) {
            int id = ids[b * CTX + c + half];
            float4 v = *(const float4*)(in_emb + (size_t)id * DIM + k0);
            s4.x += v.x; s4.y += v.y; s4.z += v.z; s4.w += v.w;
        }
        s4.x += __shfl_xor(s4.x, 32, 64);
        s4.y += __shfl_xor(s4.y, 32, 64);
        s4.z += __shfl_xor(s4.z, 32, 64);
        s4.w += __shfl_xor(s4.w, 32, 64);

        if (half == 0) {
            ushort4 hb;
            hb.x = f2bf(s4.x); hb.y = f2bf(s4.y); hb.z = f2bf(s4.z); hb.w = f2bf(s4.w);
            *(ushort4*)(h_frag + frag_off(b, k0)) = hb;
        }
        int lab = labels[b];
        float4 w4 = *(const float4*)(out_emb + (size_t)lab * DIM + k0);
        float prod = s4.x * w4.x + s4.y * w4.y + s4.z * w4.z + s4.w * w4.w;
#pragma unroll
        for (int mm = 16; mm > 0; mm >>= 1) prod += __shfl_xor(prod, mm, 64);
        if (lane == 0) tl[b] = prod + bias[lab] - log_expected_count(lab);
    } else {
        int s = (task - BATCH) * 2 + half;
        int sid = sampled[s];
        float4 v = *(const float4*)(out_emb + (size_t)sid * DIM + k0);
        ushort4 wb;
        wb.x = f2bf(v.x); wb.y = f2bf(v.y); wb.z = f2bf(v.z); wb.w = f2bf(v.w);
        *(ushort4*)(w_frag + frag_off(s, k0)) = wb;
        if (m == 0) sb[s] = bias[sid] - log_expected_count(sid);
    }
}

// ---- kernel 2: 256x128-tile bf16 MFMA GEMM fused with bias/mask/exp/row-sums
//      AND the final per-row reduction (last-arriver block per 256-row group).
__global__ __launch_bounds__(256, 2) void k_gemm_lse(
    const unsigned short* __restrict__ h_frag, const unsigned short* __restrict__ w_frag,
    const float* __restrict__ sb, const int* __restrict__ sampled,
    const int* __restrict__ labels, float* __restrict__ partials,
    const float* __restrict__ tl, float* __restrict__ out,
    unsigned int* __restrict__ counters) {
    __shared__ __align__(16) unsigned short ldsb[16384];   // 32KB
    int tid  = threadIdx.x;
    int lane = tid & 63;
    int wv   = tid >> 6;
    int r16  = lane & 15;
    int kg   = lane >> 4;
    int rbase = blockIdx.x * 256 + wv * 64;
    int cbase = blockIdx.y * 128;

    // stage B via async global->LDS, 16B/lane, linear layout
    const unsigned short* wsrc = w_frag + (size_t)cbase * 128;
#pragma unroll
    for (int i = 0; i < 8; ++i) {
        int eo = (i * 256 + tid) * 8;            // ushort offset, lane-contiguous
        __builtin_amdgcn_global_load_lds(
            (const __attribute__((address_space(1))) unsigned int*)(wsrc + eo),
            (__attribute__((address_space(3))) unsigned int*)(ldsb + eo),
            16, 0, 0);
    }

    // A fragments: 4 row-tiles x 4 ks, coalesced 1KB wave-loads (L2-resident)
    short8 a[4][4];
#pragma unroll
    for (int rt = 0; rt < 4; ++rt)
#pragma unroll
        for (int ks = 0; ks < 4; ++ks)
            a[rt][ks] = *(const short8*)(h_frag +
                (size_t)((((rbase >> 4) + rt) * 4 + ks) * 512) + lane * 8);

    f32x4 acc[4][8];
#pragma unroll
    for (int rt = 0; rt < 4; ++rt)
#pragma unroll
        for (int t = 0; t < 8; ++t) acc[rt][t] = (f32x4){0.f, 0.f, 0.f, 0.f};

    __syncthreads();
#pragma unroll
    for (int t = 0; t < 8; ++t) {
#pragma unroll
        for (int ks = 0; ks < 4; ++ks) {
            short8 bv = *(const short8*)(ldsb + (t * 4 + ks) * 512 + lane * 8);
#pragma unroll
            for (int rt = 0; rt < 4; ++rt)
                acc[rt][t] = __builtin_amdgcn_mfma_f32_16x16x32_bf16(a[rt][ks], bv, acc[rt][t], 0, 0, 0);
        }
    }

    int lab[4][4];
    float rsum[4][4];
#pragma unroll
    for (int rt = 0; rt < 4; ++rt)
#pragma unroll
        for (int r = 0; r < 4; ++r) {
            lab[rt][r]  = labels[rbase + rt * 16 + kg * 4 + r];
            rsum[rt][r] = 0.f;
        }
#pragma unroll
    for (int t = 0; t < 8; ++t) {
        int col = cbase + t * 16 + r16;                   // C/D col = lane&15
        float sbv = sb[col];
        int   sid = sampled[col];
#pragma unroll
        for (int rt = 0; rt < 4; ++rt)
#pragma unroll
            for (int r = 0; r < 4; ++r) {
                float logit = acc[rt][t][r] + sbv;
                if (sid != lab[rt][r]) rsum[rt][r] += __expf(logit);
            }
    }
#pragma unroll
    for (int m = 1; m < 16; m <<= 1)
#pragma unroll
        for (int rt = 0; rt < 4; ++rt)
#pragma unroll
            for (int r = 0; r < 4; ++r)
                rsum[rt][r] += __shfl_xor(rsum[rt][r], m, 64);
    if (r16 == 0)
#pragma unroll
        for (int rt = 0; rt < 4; ++rt)
#pragma unroll
            for (int r = 0; r < 4; ++r)
                partials[(size_t)(rbase + rt * 16 + kg * 4 + r) * NCHUNK + blockIdx.y] = rsum[rt][r];

    // ---- last-arriver final reduction for this 256-row group
    __threadfence();                                      // release partials
    __shared__ unsigned int s_old;
    __syncthreads();                                      // all stores issued
    if (tid == 0) s_old = atomicAdd(&counters[blockIdx.x], 1u);
    __syncthreads();
    if (s_old == NCHUNK - 1) {
        __threadfence();                                  // acquire partials
        int row = blockIdx.x * 256 + tid;                 // one row per thread
        const float* p = partials + (size_t)row * NCHUNK;
        float s = 0.f;
#pragma unroll
        for (int c = 0; c < NCHUNK; ++c) s += p[c];
        float t = tl[row];
        out[row] = logf(s + __expf(t)) - t;
    }
}

extern "C" void kernel_launch(void* const* d_in, const int* in_sizes, int n_in,
                              void* d_out, int out_size, void* d_ws, size_t ws_size,
                              hipStream_t stream) {
    const int*   ids     = (const int*)d_in[0];   // integers arrive as int32
    const int*   labels  = (const int*)d_in[1];
    const int*   sampled = (const int*)d_in[2];
    const float* in_emb  = (const float*)d_in[3];
    const float* out_emb = (const float*)d_in[4];
    const float* bias    = (const float*)d_in[5];
    float* out = (float*)d_out;

    char* ws = (char*)d_ws;
    unsigned short* h_frag = (unsigned short*)(ws);                     // 1 MB
    unsigned short* w_frag = (unsigned short*)(ws + (1u << 20));        // 2 MB
    float* tl       = (float*)(ws + 3u * (1u << 20));                   // 16 KB
    float* sb       = (float*)(ws + 3u * (1u << 20) + (1u << 16));      // 32 KB
    float* partials = (float*)(ws + 3u * (1u << 20) + (1u << 16) + (1u << 15)); // 1 MB
    unsigned int* counters = (unsigned int*)(ws + 5u * (1u << 20));     // 64 B

    // tasks: 4096 h-rows (1/wave) + 4096 w-pairs (2 rows/wave) = 8192 waves
    k_prep<<<dim3((BATCH + NSAMP / 2) / 4), dim3(256), 0, stream>>>(
        ids, labels, sampled, in_emb, out_emb, bias, h_frag, w_frag, tl, sb, counters);
    k_gemm_lse<<<dim3(BATCH / 256, NSAMP / 128), dim3(256), 0, stream>>>(
        h_frag, w_frag, sb, sampled, labels, partials, tl, out, counters);
}

// Round 18
// 34.468 us; speedup vs baseline: 4.4423x; 4.4423x over previous
//
#include <hip/hip_runtime.h>
#include <hip/hip_bf16.h>
#include <math.h>

#define BATCH 4096
#define CTX 20
#define DIM 128
#define NSAMP 8192
#define NCHUNK 64   // 8192 / 128 column-chunks in the GEMM kernel

typedef __attribute__((ext_vector_type(8))) short short8;
typedef __attribute__((ext_vector_type(4))) float f32x4;

__device__ __forceinline__ unsigned short f2bf(float x) {
    union { float f; unsigned u; } v; v.f = x;
    unsigned r = v.u + 0x7FFFu + ((v.u >> 16) & 1u);   // round-to-nearest-even
    return (unsigned short)(r >> 16);
}

// ---- Eigen plog<float>, EXACT op schedule — VERIFIED BIT-MATCH vs the
// harness np reference (R13 pass). DO NOT TOUCH.
__device__ __forceinline__ float eigen_plogf(float xf) {
    union { float f; unsigned u; } v; v.f = xf;    // x >= 1, normal, finite
    int ei = (int)((v.u >> 23) & 0xFFu) - 126;     // pfrexp: x = m*2^e, m in [0.5,1)
    v.u = (v.u & 0x007FFFFFu) | 0x3F000000u;
    float x = v.f;
    float e = (float)ei;
    bool msk = x < 0.707106781186547524f;          // x < SQRTHF
    float tmp = msk ? x : 0.0f;                    // pand(x, mask)
    x = __fsub_rn(x, 1.0f);
    e = __fsub_rn(e, msk ? 1.0f : 0.0f);
    x = __fadd_rn(x, tmp);

    float x2 = __fmul_rn(x, x);
    float x3 = __fmul_rn(x2, x);

    float y, y1, y2;
    y  = __builtin_fmaf( 7.0376836292E-2f, x, -1.1514610310E-1f);  // p0,p1
    y1 = __builtin_fmaf(-1.2420140846E-1f, x,  1.4249322787E-1f);  // p3,p4
    y2 = __builtin_fmaf( 2.0000714765E-1f, x, -2.4999993993E-1f);  // p6,p7
    y  = __builtin_fmaf(y,  x,  1.1676998740E-1f);                 // +p2
    y1 = __builtin_fmaf(y1, x, -1.6668057665E-1f);                 // +p5
    y2 = __builtin_fmaf(y2, x,  3.3333331174E-1f);                 // +p8
    y  = __builtin_fmaf(y,  x3, y1);
    y  = __builtin_fmaf(y,  x3, y2);
    y  = __fmul_rn(y, x3);                         // pmul

    y1  = __fmul_rn(e, -2.12194440e-4f);           // pmul (q1) — NOT fused
    tmp = __fmul_rn(x2, 0.5f);                     // pmul — NOT fused
    y   = __fadd_rn(y, y1);                        // padd
    x   = __fsub_rn(x, tmp);                       // psub (x first!)
    y2  = __fmul_rn(e, 0.693359375f);              // pmul (q2) — NOT fused
    x   = __fadd_rn(x, y);                         // padd
    x   = __fadd_rn(x, y2);                        // padd
    return x;
}

__device__ __forceinline__ float log_expected_count(int id) {
    float idf = (float)id;                           // exact (id < 2^24)
    float l2 = eigen_plogf(__fadd_rn(idf, 2.0f));
    float l1 = eigen_plogf(__fadd_rn(idf, 1.0f));
    float num = __fsub_rn(l2, l1);                   // the f32 cancellation
    float logH = eigen_plogf(1000001.0f);
    float p = num / logH;
    float t = __fmul_rn(8192.0f, log1pf(-p));        // *2^13 exact
    float e = -expm1f(t);
    e = fmaxf(e, 1e-38f);
    return logf(e);
}

// Fragment layout: element (row, k) of a [N x 128] bf16 matrix lives at
// ushort offset ((row>>4)*4 + (k>>5))*512 + (((k>>3)&3)*16 + (row&15))*8 + (k&7).
__device__ __forceinline__ size_t frag_off(int row, int k0) {
    return (size_t)(((row >> 4) * 4 + (k0 >> 5)) * 512) +
           ((((k0 >> 3) & 3) * 16 + (row & 15)) * 8) + (k0 & 7);
}

// ---- kernel 1: 256-thread blocks, 1 wave = 1 task (R16-verified).
__global__ __launch_bounds__(256) void k_prep(
        const int* __restrict__ ids, const int* __restrict__ labels,
        const int* __restrict__ sampled,
        const float* __restrict__ in_emb, const float* __restrict__ out_emb,
        const float* __restrict__ bias,
        unsigned short* __restrict__ h_frag, unsigned short* __restrict__ w_frag,
        float* __restrict__ tl, float* __restrict__ sb) {
    int tid  = threadIdx.x;
    int lane = tid & 63;
    int wv   = tid >> 6;
    int task = blockIdx.x * 4 + wv;
    int half = lane >> 5;             // 0: lanes 0-31, 1: lanes 32-63
    int m    = lane & 31;             // dim group: dims 4m..4m+3
    int k0   = 4 * m;

    if (task < BATCH) {
        int b = task;
        float4 s4 = make_float4(0.f, 0.f, 0.f, 0.f);
#pragma unroll
        for (int c = 0; c < CTX; c += 2) {
            int id = ids[b * CTX + c + half];
            float4 v = *(const float4*)(in_emb + (size_t)id * DIM + k0);
            s4.x += v.x; s4.y += v.y; s4.z += v.z; s4.w += v.w;
        }
        s4.x += __shfl_xor(s4.x, 32, 64);
        s4.y += __shfl_xor(s4.y, 32, 64);
        s4.z += __shfl_xor(s4.z, 32, 64);
        s4.w += __shfl_xor(s4.w, 32, 64);

        if (half == 0) {
            ushort4 hb;
            hb.x = f2bf(s4.x); hb.y = f2bf(s4.y); hb.z = f2bf(s4.z); hb.w = f2bf(s4.w);
            *(ushort4*)(h_frag + frag_off(b, k0)) = hb;
        }
        int lab = labels[b];
        float4 w4 = *(const float4*)(out_emb + (size_t)lab * DIM + k0);
        float prod = s4.x * w4.x + s4.y * w4.y + s4.z * w4.z + s4.w * w4.w;
#pragma unroll
        for (int mm = 16; mm > 0; mm >>= 1) prod += __shfl_xor(prod, mm, 64);
        if (lane == 0) tl[b] = prod + bias[lab] - log_expected_count(lab);
    } else {
        int s = (task - BATCH) * 2 + half;
        int sid = sampled[s];
        float4 v = *(const float4*)(out_emb + (size_t)sid * DIM + k0);
        ushort4 wb;
        wb.x = f2bf(v.x); wb.y = f2bf(v.y); wb.z = f2bf(v.z); wb.w = f2bf(v.w);
        *(ushort4*)(w_frag + frag_off(s, k0)) = wb;
        if (m == 0) sb[s] = bias[sid] - log_expected_count(sid);
    }
}

// ---- kernel 2: 128x128-tile bf16 MFMA GEMM fused with bias/mask/exp/row-sums.
//      4 waves x 32 rows (rt=2) -> VGPR ~140, 3 blocks/CU co-resident
//      (R14's sweet spot: staging-latency-bound, occupancy > ds_read ratio).
__global__ __launch_bounds__(256, 3) void k_gemm_lse(
    const unsigned short* __restrict__ h_frag, const unsigned short* __restrict__ w_frag,
    const float* __restrict__ sb, const int* __restrict__ sampled,
    const int* __restrict__ labels, float* __restrict__ partials) {
    __shared__ __align__(16) unsigned short ldsb[16384];   // 32KB
    int tid  = threadIdx.x;
    int lane = tid & 63;
    int wv   = tid >> 6;
    int r16  = lane & 15;
    int kg   = lane >> 4;
    int rbase = blockIdx.x * 128 + wv * 32;
    int cbase = blockIdx.y * 128;

    // stage B via async global->LDS, 16B/lane, linear layout
    const unsigned short* wsrc = w_frag + (size_t)cbase * 128;
#pragma unroll
    for (int i = 0; i < 8; ++i) {
        int eo = (i * 256 + tid) * 8;            // ushort offset, lane-contiguous
        __builtin_amdgcn_global_load_lds(
            (const __attribute__((address_space(1))) unsigned int*)(wsrc + eo),
            (__attribute__((address_space(3))) unsigned int*)(ldsb + eo),
            16, 0, 0);
    }

    // A fragments: 2 row-tiles x 4 ks, coalesced 1KB wave-loads (L2-resident)
    short8 a[2][4];
#pragma unroll
    for (int rt = 0; rt < 2; ++rt)
#pragma unroll
        for (int ks = 0; ks < 4; ++ks)
            a[rt][ks] = *(const short8*)(h_frag +
                (size_t)((((rbase >> 4) + rt) * 4 + ks) * 512) + lane * 8);

    f32x4 acc[2][8];
#pragma unroll
    for (int rt = 0; rt < 2; ++rt)
#pragma unroll
        for (int t = 0; t < 8; ++t) acc[rt][t] = (f32x4){0.f, 0.f, 0.f, 0.f};

    __syncthreads();
#pragma unroll
    for (int t = 0; t < 8; ++t) {
#pragma unroll
        for (int ks = 0; ks < 4; ++ks) {
            short8 bv = *(const short8*)(ldsb + (t * 4 + ks) * 512 + lane * 8);
#pragma unroll
            for (int rt = 0; rt < 2; ++rt)
                acc[rt][t] = __builtin_amdgcn_mfma_f32_16x16x32_bf16(a[rt][ks], bv, acc[rt][t], 0, 0, 0);
        }
    }

    int lab[2][4];
    float rsum[2][4];
#pragma unroll
    for (int rt = 0; rt < 2; ++rt)
#pragma unroll
        for (int r = 0; r < 4; ++r) {
            lab[rt][r]  = labels[rbase + rt * 16 + kg * 4 + r];
            rsum[rt][r] = 0.f;
        }
#pragma unroll
    for (int t = 0; t < 8; ++t) {
        int col = cbase + t * 16 + r16;                   // C/D col = lane&15
        float sbv = sb[col];
        int   sid = sampled[col];
#pragma unroll
        for (int rt = 0; rt < 2; ++rt)
#pragma unroll
            for (int r = 0; r < 4; ++r) {
                float logit = acc[rt][t][r] + sbv;
                if (sid != lab[rt][r]) rsum[rt][r] += __expf(logit);
            }
    }
#pragma unroll
    for (int m = 1; m < 16; m <<= 1)
#pragma unroll
        for (int rt = 0; rt < 2; ++rt)
#pragma unroll
            for (int r = 0; r < 4; ++r)
                rsum[rt][r] += __shfl_xor(rsum[rt][r], m, 64);
    if (r16 == 0)
#pragma unroll
        for (int rt = 0; rt < 2; ++rt)
#pragma unroll
            for (int r = 0; r < 4; ++r)
                partials[(size_t)(rbase + rt * 16 + kg * 4 + r) * NCHUNK + blockIdx.y] = rsum[rt][r];
}

// ---- kernel 3: loss[b] = log(sum_chunks + exp(tl)) - tl
__global__ void k_reduce(const float* __restrict__ partials, const float* __restrict__ tl,
                         float* __restrict__ out) {
    int row  = blockIdx.x * 4 + (threadIdx.x >> 6);
    int lane = threadIdx.x & 63;
    float s = partials[(size_t)row * NCHUNK + lane];
#pragma unroll
    for (int m = 32; m > 0; m >>= 1) s += __shfl_xor(s, m, 64);
    if (lane == 0) {
        float t = tl[row];
        out[row] = logf(s + __expf(t)) - t;
    }
}

extern "C" void kernel_launch(void* const* d_in, const int* in_sizes, int n_in,
                              void* d_out, int out_size, void* d_ws, size_t ws_size,
                              hipStream_t stream) {
    const int*   ids     = (const int*)d_in[0];   // integers arrive as int32
    const int*   labels  = (const int*)d_in[1];
    const int*   sampled = (const int*)d_in[2];
    const float* in_emb  = (const float*)d_in[3];
    const float* out_emb = (const float*)d_in[4];
    const float* bias    = (const float*)d_in[5];
    float* out = (float*)d_out;

    char* ws = (char*)d_ws;
    unsigned short* h_frag = (unsigned short*)(ws);                     // 1 MB
    unsigned short* w_frag = (unsigned short*)(ws + (1u << 20));        // 2 MB
    float* tl       = (float*)(ws + 3u * (1u << 20));                   // 16 KB
    float* sb       = (float*)(ws + 3u * (1u << 20) + (1u << 16));      // 32 KB
    float* partials = (float*)(ws + 3u * (1u << 20) + (1u << 16) + (1u << 15)); // 1 MB

    // tasks: 4096 h-rows (1/wave) + 4096 w-pairs (2 rows/wave) = 8192 waves
    k_prep<<<dim3((BATCH + NSAMP / 2) / 4), dim3(256), 0, stream>>>(
        ids, labels, sampled, in_emb, out_emb, bias, h_frag, w_frag, tl, sb);
    k_gemm_lse<<<dim3(BATCH / 128, NSAMP / 128), dim3(256), 0, stream>>>(
        h_frag, w_frag, sb, sampled, labels, partials);
    k_reduce<<<dim3(BATCH / 4), dim3(256), 0, stream>>>(partials, tl, out);
}